// Round 8
// baseline (225.184 us; speedup 1.0000x reference)
//
#include <hip/hip_runtime.h>
#include <hip/hip_bf16.h>

#define NROWS 16384
#define DIM 128
#define TAU_INV 14.285714285714285714f
#define K1_CONST 20.6099273650808706f /* log2(e)/tau ; exp(cos/tau) = 2^(K1*cos) */

typedef __attribute__((ext_vector_type(8))) __bf16 bf16x8;
typedef __attribute__((ext_vector_type(4))) float f32x4;
typedef unsigned int u32;
typedef unsigned short u16;

#if __has_builtin(__builtin_amdgcn_exp2f)
#define EXP2F(x) __builtin_amdgcn_exp2f(x)
#else
#define EXP2F(x) exp2f(x)
#endif

__device__ __forceinline__ u16 f2bf(float x) {
  __hip_bfloat16 h = __float2bfloat16(x);
  return *reinterpret_cast<u16*>(&h);
}

__device__ __forceinline__ void gload_lds16(const void* g, void* l) {
  __builtin_amdgcn_global_load_lds(
      (const __attribute__((address_space(1))) u32*)g,
      (__attribute__((address_space(3))) u32*)l, 16, 0, 0);
}

// ------- Kernel A: normalize -> z1q (K1-scaled Q), z1c/z2c (unit), pos -----
__global__ __launch_bounds__(256) void nrm_kernel(
    const float* __restrict__ z1, const float* __restrict__ z2,
    u16* __restrict__ z1q, u16* __restrict__ z1c, u16* __restrict__ z2c,
    float* __restrict__ pos_sim)
{
  const int tid  = threadIdx.x;
  const int lane = tid & 63, wid = tid >> 6;
  const int row  = blockIdx.x * 4 + wid;
  const float2 a = *(const float2*)(z1 + (size_t)row * DIM + lane * 2);
  const float2 b = *(const float2*)(z2 + (size_t)row * DIM + lane * 2);
  float ss1 = a.x * a.x + a.y * a.y;
  float ss2 = b.x * b.x + b.y * b.y;
  float dd  = a.x * b.x + a.y * b.y;
#pragma unroll
  for (int d = 1; d < 64; d <<= 1) {
    ss1 += __shfl_xor(ss1, d);
    ss2 += __shfl_xor(ss2, d);
    dd  += __shfl_xor(dd,  d);
  }
  const float inv1 = 1.0f / fmaxf(sqrtf(ss1), 1e-12f);
  const float inv2 = 1.0f / fmaxf(sqrtf(ss2), 1e-12f);
  const float s1q = inv1 * K1_CONST;
  u32 pq = (u32)f2bf(a.x * s1q) | ((u32)f2bf(a.y * s1q) << 16);
  u32 p1 = (u32)f2bf(a.x * inv1) | ((u32)f2bf(a.y * inv1) << 16);
  u32 p2 = (u32)f2bf(b.x * inv2) | ((u32)f2bf(b.y * inv2) << 16);
  ((u32*)z1q)[(size_t)row * (DIM / 2) + lane] = pq;
  ((u32*)z1c)[(size_t)row * (DIM / 2) + lane] = p1;
  ((u32*)z2c)[(size_t)row * (DIM / 2) + lane] = p2;
  if (lane == 0) pos_sim[row] = dd * inv1 * inv2 * TAU_INV;
}

// ------ Kernel B: fused GEMM + sum(2^score), wave-private, ZERO barriers ----
// grid = 1024 : ch = bx>>6 (16 chunks of 2048 cols), rb = (bx&63)*4+wid.
// Each wave: 64 q-rows x 2048 cols as 128 private 16-col tiles (4 KB each),
// self-staged via 4 gload_lds + per-wave counted vmcnt. No s_barrier at all:
// waves de-phase so one wave's exp burst overlaps another's MFMA occupancy
// (rounds 4-7: barrier phase-lock -> MFMA 60us + VALU 60us serialized).
__global__ __launch_bounds__(256, 3) void lse_kernel(
    const u16* __restrict__ z1q, const u16* __restrict__ z1c,
    const u16* __restrict__ z2c, float* __restrict__ lparts)
{
  __shared__ __attribute__((aligned(16))) char smem[49152]; // 4 waves x 3 x 4KB
  const int tid    = threadIdx.x;
  const int lane   = tid & 63, wid = tid >> 6;
  const int ch     = blockIdx.x >> 6;
  const int rb     = (blockIdx.x & 63) * 4 + wid;
  const int qb     = rb * 64;
  const int lane15 = lane & 15, laneHi = lane >> 4;

  // Q fragments (B-operand 16x16x32): lane -> (qrow=lane15, k=ks*32+laneHi*8+i)
  bf16x8 qf[4][4];
#pragma unroll
  for (int qg = 0; qg < 4; ++qg)
#pragma unroll
    for (int ks = 0; ks < 4; ++ks)
      qf[qg][ks] = *(const bf16x8*)(z1q + (size_t)(qb + qg * 16 + lane15) * DIM +
                                    ks * 32 + laneHi * 8);

  const u16* zt = (ch < 8) ? (z2c + (size_t)ch * 2048 * DIM)
                           : (z1c + (size_t)(ch - 8) * 2048 * DIM);
  int t0 = -100; // first diag tile (4 consecutive) or none
  if (ch >= 8) {
    const int d = qb - (ch - 8) * 2048;
    if (d >= 0 && d < 2048) t0 = d >> 4;
  }

  // staging source offsets: granule g holds rows 4g..4g+3; lane s -> row
  // 4g+(s>>4), LDS chunk s&15, global chunk (s&15)^(row&15) (4-bit XOR swz)
  int goff[4];
#pragma unroll
  for (int g = 0; g < 4; ++g) {
    const int row = g * 4 + (lane >> 4);
    goff[g] = row * 256 + (((lane & 15) ^ (row & 15)) << 4);
  }
  const char* const srcb = (const char*)zt;
  char* const wbase = smem + wid * 12288; // 3 private 4KB buffers

  // A-frag read offsets: row=lane15 (col), chunk=(ks*4+laneHi)^lane15 -> 0-conflict
  int aoff[4];
#pragma unroll
  for (int ks = 0; ks < 4; ++ks)
    aoff[ks] = lane15 * 256 + ((((ks << 2) + laneHi) ^ lane15) << 4);

  const f32x4 Z4 = {0.f, 0.f, 0.f, 0.f};
  float2 lacc[4] = {{0.f,0.f},{0.f,0.f},{0.f,0.f},{0.f,0.f}};
  const int jm = lane15 - laneHi * 4; // diag j-index for this lane (valid 0..3)

  auto stage = [&](int t, int so) { // 4 gloads: tile t -> wave buffer so
    const char* s = srcb + (size_t)t * 4096;
    char* d = wbase + so;
#pragma unroll
    for (int g = 0; g < 4; ++g)
      gload_lds16(s + goff[g], d + (g << 10));
  };

  // prologue: stage tiles 0,1 (after 16 qf loads -> all retired by vmcnt(4))
  stage(0, 0);
  stage(1, 4096);

  int bo = 0; // buffer offset of tile t: rotates 0,4096,8192
#pragma unroll 1
  for (int t = 0; t < 128; ++t) {
    // retire tile t's 4 loads (leave t+1's in flight); tail drains fully
    if (t < 127) asm volatile("s_waitcnt vmcnt(4)" ::: "memory");
    else         asm volatile("s_waitcnt vmcnt(0)" ::: "memory");
    if (t + 2 < 128) {
      int so = bo - 4096; if (so < 0) so += 12288; // (bo+8192)%12288
      stage(t + 2, so);
    }
    bf16x8 af[4];
#pragma unroll
    for (int ks = 0; ks < 4; ++ks)
      af[ks] = *(const bf16x8*)(wbase + bo + aoff[ks]);
    f32x4 acc[4];
    __builtin_amdgcn_s_setprio(1);
#pragma unroll
    for (int qg = 0; qg < 4; ++qg)
      acc[qg] = __builtin_amdgcn_mfma_f32_16x16x32_bf16(af[0], qf[qg][0], Z4, 0, 0, 0);
#pragma unroll
    for (int ks = 1; ks < 4; ++ks)
#pragma unroll
      for (int qg = 0; qg < 4; ++qg)
        acc[qg] = __builtin_amdgcn_mfma_f32_16x16x32_bf16(af[ks], qf[qg][ks],
                                                          acc[qg], 0, 0, 0);
    __builtin_amdgcn_s_setprio(0);

    const int dq = t - t0; // 0..3 -> acc[dq] holds this tile's diagonal
    if ((u32)dq < 4u) {
#pragma unroll
      for (int qg = 0; qg < 4; ++qg) {
        float e0 = EXP2F(acc[qg][0]), e1 = EXP2F(acc[qg][1]);
        float e2 = EXP2F(acc[qg][2]), e3 = EXP2F(acc[qg][3]);
        if (qg == dq) { // zero score(qrow==col): lane15 == laneHi*4 + j
          if (jm == 0) e0 = 0.f;
          if (jm == 1) e1 = 0.f;
          if (jm == 2) e2 = 0.f;
          if (jm == 3) e3 = 0.f;
        }
        float2 p0; p0.x = e0; p0.y = e1;
        float2 p1; p1.x = e2; p1.y = e3;
        lacc[qg] += p0; lacc[qg] += p1;
      }
    } else {
#pragma unroll
      for (int qg = 0; qg < 4; ++qg) {
        float2 p0, p1;
        p0.x = EXP2F(acc[qg][0]); p0.y = EXP2F(acc[qg][1]);
        p1.x = EXP2F(acc[qg][2]); p1.y = EXP2F(acc[qg][3]);
        lacc[qg] += p0; lacc[qg] += p1;
      }
    }
    bo = (bo == 8192) ? 0 : bo + 4096;
  }

  // per q-row total: reduce over laneHi groups (cols are spread across laneHi)
#pragma unroll
  for (int qg = 0; qg < 4; ++qg) {
    float l = lacc[qg].x + lacc[qg].y;
    l += __shfl_xor(l, 16);
    l += __shfl_xor(l, 32);
    if (lane < 16)
      lparts[(size_t)ch * NROWS + qb + qg * 16 + lane15] = l;
  }
}

// ---------------- Kernel C: finalize (32 blocks, atomic into out) ----------
// P_i = sum 2^(K1*cos) = sum exp(s_i) exactly -> lse = ln(P_i), no bias term
__global__ __launch_bounds__(256) void fin_kernel(
    const float* __restrict__ lparts, const float* __restrict__ pos,
    float* __restrict__ out)
{
  __shared__ float red[4];
  const int tid = threadIdx.x, bx = blockIdx.x;
  float s = 0.f;
#pragma unroll 1
  for (int i = bx * 512 + tid; i < (bx + 1) * 512; i += 256) {
    float l = 0.f;
#pragma unroll
    for (int c = 0; c < 16; ++c) l += lparts[(size_t)c * NROWS + i];
    s += logf(l) - pos[i];
  }
#pragma unroll
  for (int d = 1; d < 64; d <<= 1) s += __shfl_xor(s, d);
  if ((tid & 63) == 0) red[tid >> 6] = s;
  __syncthreads();
  if (tid == 0) {
    float t = (red[0] + red[1]) + (red[2] + red[3]);
    atomicAdd(out, t / (float)NROWS);
  }
}

extern "C" void kernel_launch(void* const* d_in, const int* in_sizes, int n_in,
                              void* d_out, int out_size, void* d_ws, size_t ws_size,
                              hipStream_t stream) {
  const float* z1 = (const float*)d_in[0];
  const float* z2 = (const float*)d_in[1];
  float* out = (float*)d_out;
  char* ws = (char*)d_ws;
  const size_t MB4 = (size_t)NROWS * DIM * 2;
  u16* z1q = (u16*)ws;                        // 4 MB (K1-scaled Q)
  u16* z1c = (u16*)(ws + MB4);                // 4 MB (unit, intra cols)
  u16* z2c = (u16*)(ws + 2 * MB4);            // 4 MB (unit, cross cols)
  float* pos = (float*)(ws + 3 * MB4);        // 64 KB
  float* lparts = (float*)(ws + 3 * MB4 + (size_t)NROWS * 4); // 1 MB

  hipMemsetAsync(d_out, 0, sizeof(float), stream);
  hipLaunchKernelGGL(nrm_kernel, dim3(NROWS / 4), dim3(256), 0, stream,
                     z1, z2, z1q, z1c, z2c, pos);
  hipLaunchKernelGGL(lse_kernel, dim3(1024), dim3(256), 0, stream,
                     z1q, z1c, z2c, lparts);
  hipLaunchKernelGGL(fin_kernel, dim3(32), dim3(256), 0, stream,
                     lparts, pos, out);
}

// Round 10
// 145.209 us; speedup vs baseline: 1.5508x; 1.5508x over previous
//
#include <hip/hip_runtime.h>
#include <hip/hip_bf16.h>

#define NROWS 16384
#define DIM 128
#define TAU_INV 14.285714285714285714f
#define K1_CONST 20.6099273650808706f /* log2(e)/tau ; exp(cos/tau) = 2^(K1*cos) */

typedef __attribute__((ext_vector_type(4))) int i32x4;
typedef __attribute__((ext_vector_type(8))) int i32x8;
typedef __attribute__((ext_vector_type(4))) float f32x4;
typedef unsigned int u32;
typedef unsigned short u16;

#if __has_builtin(__builtin_amdgcn_exp2f)
#define EXP2F(x) __builtin_amdgcn_exp2f(x)
#else
#define EXP2F(x) exp2f(x)
#endif

// pack two floats -> two OCP e4m3 bytes (HW cvt; byte order irrelevant for the
// GEMM: the same k-permutation is applied to BOTH operands -> result invariant)
__device__ __forceinline__ u16 pk8(float x, float y) {
  return (u16)(__builtin_amdgcn_cvt_pk_fp8_f32(x, y, 0, false) & 0xffff);
}

__device__ __forceinline__ void gload_lds16(const void* g, void* l) {
  __builtin_amdgcn_global_load_lds(
      (const __attribute__((address_space(1))) u32*)g,
      (__attribute__((address_space(3))) u32*)l, 16, 0, 0);
}

// ------- Kernel A: normalize -> z1q8 (K1-scaled fp8 Q), zc8 (unit fp8 cols:
// rows [0,N) = z2 (cross view), rows [N,2N) = z1 (intra view)), pos (fp32) ---
__global__ __launch_bounds__(256) void nrm_kernel(
    const float* __restrict__ z1, const float* __restrict__ z2,
    u16* __restrict__ z1q8, u16* __restrict__ zc8, float* __restrict__ pos_sim)
{
  const int tid  = threadIdx.x;
  const int lane = tid & 63, wid = tid >> 6;
  const int row  = blockIdx.x * 4 + wid;
  const float2 a = *(const float2*)(z1 + (size_t)row * DIM + lane * 2);
  const float2 b = *(const float2*)(z2 + (size_t)row * DIM + lane * 2);
  float ss1 = a.x * a.x + a.y * a.y;
  float ss2 = b.x * b.x + b.y * b.y;
  float dd  = a.x * b.x + a.y * b.y;
#pragma unroll
  for (int d = 1; d < 64; d <<= 1) {
    ss1 += __shfl_xor(ss1, d);
    ss2 += __shfl_xor(ss2, d);
    dd  += __shfl_xor(dd,  d);
  }
  const float inv1 = 1.0f / fmaxf(sqrtf(ss1), 1e-12f);
  const float inv2 = 1.0f / fmaxf(sqrtf(ss2), 1e-12f);
  const float s1q = inv1 * K1_CONST;
  z1q8[(size_t)row * 64 + lane] = pk8(a.x * s1q, a.y * s1q);
  zc8[(size_t)(NROWS + row) * 64 + lane] = pk8(a.x * inv1, a.y * inv1);
  zc8[(size_t)row * 64 + lane]           = pk8(b.x * inv2, b.y * inv2);
  if (lane == 0) pos_sim[row] = dd * inv1 * inv2 * TAU_INV;
}

// ---------- Kernel B: fused fp8-MX GEMM (K=128 in ONE mfma) + sum(2^s) ------
// grid = 1024 : rb = bx&63 (256 q-rows), ch = bx>>6 (16 chunks of 2048 cols)
// 4 waves/block, each wave: 64 q-rows (4 groups of 16), shared 64-col tiles.
// mfma_scale_f32_16x16x128_f8f6f4 @ ~4686 TF: MFMA pipe 66 -> 29 us vs bf16.
// Scales = identity (0x7F = e8m0 1.0) -> no scale-block layout dependence.
__global__ __launch_bounds__(256, 3) void lse_kernel(
    const u16* __restrict__ z1q8, const u16* __restrict__ zc8,
    float* __restrict__ lparts)
{
  __shared__ __attribute__((aligned(16))) char smem[16384]; // 2 x 64x128 fp8
  const int tid    = threadIdx.x;
  const int lane   = tid & 63, wid = tid >> 6;
  const int rb     = blockIdx.x & 63, ch = blockIdx.x >> 6;
  const int lane15 = lane & 15, laneHi = lane >> 4;
  const int qb     = rb * 256 + wid * 64; // this wave's first q-row

  // Q fragments (B-operand): col=lane15 (q-row), k-bytes = laneHi*32..+31
  i32x8 qf[4];
#pragma unroll
  for (int qg = 0; qg < 4; ++qg)
    qf[qg] = *(const i32x8*)((const char*)z1q8 +
              (size_t)(qb + qg * 16 + lane15) * 128 + laneHi * 32);

  const char* const zt = (const char*)zc8 + (size_t)ch * 2048 * 128;
  int t_diag = -100;
  if (ch >= 8) {
    const int d = qb - (ch - 8) * 2048;
    if (d >= 0 && d < 2048) t_diag = d >> 6;
  }

  // staging: LDS[r][c] = G[r][c ^ (r&7)] (16B chunks, 8/row). 2 gloads/thread.
  int soff[2], doff[2];
#pragma unroll
  for (int g = 0; g < 2; ++g) {
    const int d = tid + g * 256, r = d >> 3, c = d & 7;
    soff[g] = r * 128 + ((c ^ (r & 7)) << 4);
    doff[g] = d << 4;
  }
  // A-frag reads: row=cb*16+lane15, G-chunks laneHi*2(+1) -> XOR row&7.
  // 8 lanes/phys-chunk = exact b128 bank floor (balanced, conflict-free).
  int aoffA[4], aoffB[4];
#pragma unroll
  for (int cb = 0; cb < 4; ++cb) {
    const int r = cb * 16 + lane15;
    aoffA[cb] = r * 128 + (((laneHi * 2) ^ (r & 7)) << 4);
    aoffB[cb] = r * 128 + (((laneHi * 2 + 1) ^ (r & 7)) << 4);
  }

  const u32 sONE = 0x7f7f7f7fu; // e8m0 127 = 2^0 in all byte slots
  const f32x4 Z4 = {0.f, 0.f, 0.f, 0.f};
  float2 lacc[4] = {{0.f,0.f},{0.f,0.f},{0.f,0.f},{0.f,0.f}};

  auto stage = [&](int t, int cur) {
    const char* s = zt + (size_t)t * 8192;
    char* d = smem + cur * 8192;
    gload_lds16(s + soff[0], d + doff[0]);
    gload_lds16(s + soff[1], d + doff[1]);
  };

  auto accum = [&](const f32x4& a, int cb, int qg, bool dtile) {
    float e0 = EXP2F(a[0]), e1 = EXP2F(a[1]);
    float e2 = EXP2F(a[2]), e3 = EXP2F(a[3]);
    if (dtile && cb == qg) { // mask col == q-row: lane15 == laneHi*4 + j
      if (lane15 == laneHi * 4 + 0) e0 = 0.f;
      if (lane15 == laneHi * 4 + 1) e1 = 0.f;
      if (lane15 == laneHi * 4 + 2) e2 = 0.f;
      if (lane15 == laneHi * 4 + 3) e3 = 0.f;
    }
    float2 p0, p1;
    p0.x = e0; p0.y = e1; p1.x = e2; p1.y = e3;
    lacc[qg] += p0; lacc[qg] += p1;
  };

  auto tile = [&](int bufo, bool dtile) {
#pragma unroll
    for (int cb = 0; cb < 4; ++cb) {
      const i32x4 lo = *(const i32x4*)(smem + bufo + aoffA[cb]);
      const i32x4 hi = *(const i32x4*)(smem + bufo + aoffB[cb]);
      const i32x8 af = __builtin_shufflevector(lo, hi, 0, 1, 2, 3, 4, 5, 6, 7);
      __builtin_amdgcn_s_setprio(1);
      f32x4 a0 = __builtin_amdgcn_mfma_scale_f32_16x16x128_f8f6f4(
          af, qf[0], Z4, 0, 0, 0, sONE, 0, sONE);
      f32x4 a1 = __builtin_amdgcn_mfma_scale_f32_16x16x128_f8f6f4(
          af, qf[1], Z4, 0, 0, 0, sONE, 0, sONE);
      f32x4 a2 = __builtin_amdgcn_mfma_scale_f32_16x16x128_f8f6f4(
          af, qf[2], Z4, 0, 0, 0, sONE, 0, sONE);
      f32x4 a3 = __builtin_amdgcn_mfma_scale_f32_16x16x128_f8f6f4(
          af, qf[3], Z4, 0, 0, 0, sONE, 0, sONE);
      __builtin_amdgcn_s_setprio(0);
      accum(a0, cb, 0, dtile);
      accum(a1, cb, 1, dtile);
      accum(a2, cb, 2, dtile);
      accum(a3, cb, 3, dtile);
    }
  };

  stage(0, 0);
  __syncthreads();
#pragma unroll 1
  for (int tt = 0; tt < 16; ++tt) {
    const int t0 = tt * 2;
    stage(t0 + 1, 1);
    tile(0, t0 == t_diag);
    __syncthreads();
    if (tt < 15) stage(t0 + 2, 0);
    tile(8192, t0 + 1 == t_diag);
    __syncthreads();
  }

  // per q-row total: cols spread across laneHi groups -> reduce 16/32
#pragma unroll
  for (int qg = 0; qg < 4; ++qg) {
    float l = lacc[qg].x + lacc[qg].y;
    l += __shfl_xor(l, 16);
    l += __shfl_xor(l, 32);
    if (lane < 16)
      lparts[(size_t)ch * NROWS + qb + qg * 16 + lane15] = l;
  }
}

// ---------------- Kernel C: finalize (32 blocks, atomic into out) ----------
// P_i = sum 2^(K1*cos) = sum exp(s_i) exactly -> lse = ln(P_i), no bias term
__global__ __launch_bounds__(256) void fin_kernel(
    const float* __restrict__ lparts, const float* __restrict__ pos,
    float* __restrict__ out)
{
  __shared__ float red[4];
  const int tid = threadIdx.x, bx = blockIdx.x;
  float s = 0.f;
#pragma unroll 1
  for (int i = bx * 512 + tid; i < (bx + 1) * 512; i += 256) {
    float l = 0.f;
#pragma unroll
    for (int c = 0; c < 16; ++c) l += lparts[(size_t)c * NROWS + i];
    s += logf(l) - pos[i];
  }
#pragma unroll
  for (int d = 1; d < 64; d <<= 1) s += __shfl_xor(s, d);
  if ((tid & 63) == 0) red[tid >> 6] = s;
  __syncthreads();
  if (tid == 0) {
    float t = (red[0] + red[1]) + (red[2] + red[3]);
    atomicAdd(out, t / (float)NROWS);
  }
}

extern "C" void kernel_launch(void* const* d_in, const int* in_sizes, int n_in,
                              void* d_out, int out_size, void* d_ws, size_t ws_size,
                              hipStream_t stream) {
  const float* z1 = (const float*)d_in[0];
  const float* z2 = (const float*)d_in[1];
  float* out = (float*)d_out;
  char* ws = (char*)d_ws;
  u16* z1q8 = (u16*)ws;                                   // 2 MB (K1-scaled Q)
  u16* zc8  = (u16*)(ws + (size_t)2 * 1024 * 1024);       // 4 MB (unit cols)
  float* pos = (float*)(ws + (size_t)6 * 1024 * 1024);    // 64 KB
  float* lparts = (float*)(ws + (size_t)6 * 1024 * 1024 + 65536); // 1 MB

  hipMemsetAsync(d_out, 0, sizeof(float), stream);
  hipLaunchKernelGGL(nrm_kernel, dim3(NROWS / 4), dim3(256), 0, stream,
                     z1, z2, z1q8, zc8, pos);
  hipLaunchKernelGGL(lse_kernel, dim3(1024), dim3(256), 0, stream,
                     z1q8, zc8, lparts);
  hipLaunchKernelGGL(fin_kernel, dim3(32), dim3(256), 0, stream,
                     lparts, pos, out);
}